// Round 8
// baseline (222.407 us; speedup 1.0000x reference)
//
#include <hip/hip_runtime.h>

// WordSAGE on MI355X — fp32 in/out. Round-8 structure:
//   k_prep  : ONE kernel = edge fillpad + train->AF fragment-order bf16 + W pack
//   k_gather: per-tile block; mean-agg gene -> AF/AFL fragment slots (coalesced)
//   k_mega  : fused 4-layer MFMA; A AND B both stream from global in fragment
//             order (every load = lane-contiguous 1KB/wave); LDS only h tiles.
// A fragment order: AF[tile][kk][lane][j]  (tile=row/16, row=tile*16+(lane&15),
// col = kk*32 + (lane>>4)*8 + j). Matches mfma_f32_16x16x32_bf16 A operand.
// Precision: split hi/lo bf16 for weights/agg/h; train hi-only (~0.004 err).

#define NG 2500
#define NT 20000
#define NE 640000
#define NCLS 16
#define CAP 96
#define NTILE 1250   // NT/16

typedef unsigned short u16;
typedef unsigned int u32;

typedef float f32x4 __attribute__((ext_vector_type(4)));
typedef __bf16 bf16x8 __attribute__((ext_vector_type(8)));

__device__ __forceinline__ float b2f(u16 u) { return __uint_as_float(((u32)u) << 16); }
__device__ __forceinline__ u16 f2b(float f) {  // RNE fp32->bf16
    u32 u = __float_as_uint(f);
    return (u16)((u + 0x7fffu + ((u >> 16) & 1u)) >> 16);
}

// ---- B-fragment pack sizes ------------------------------------------------
#define B1N 81920   // K=640: train k 0..499, zero 500..511, agg 512..639; N=128
#define B2N 32768   // K=256: h1 (W2s) 0..127, agg (W2n) 128..255; N=128
#define B3N 16384   // K=128 Wc1, N=128
#define B4N 2048    // K=128 Wc2, N=16
#define NEB 2500    // edge blocks
#define CVB 5000    // convert blocks (1250 tiles * 16 kk * 64 lanes / 256)
#define PKB 520     // pack blocks ((B1N+B2N+B3N+B4N)/256)

// ---- fused prep: fillpad edges | train->AF hi | weight pack ---------------
__global__ __launch_bounds__(256) void k_prep(
    const int* __restrict__ esrc, const int* __restrict__ edst,
    int* __restrict__ cnt, u16* __restrict__ csr,
    const float* __restrict__ train, u16* __restrict__ AF,
    const float* __restrict__ W1n, const float* __restrict__ W1s,
    const float* __restrict__ W2n, const float* __restrict__ W2s,
    const float* __restrict__ Wc1, const float* __restrict__ Wc2,
    u16* __restrict__ B1h, u16* __restrict__ B1l,
    u16* __restrict__ B2h, u16* __restrict__ B2l,
    u16* __restrict__ B3h, u16* __restrict__ B3l,
    u16* __restrict__ B4h, u16* __restrict__ B4l) {
    int blk = blockIdx.x, t = threadIdx.x;
    if (blk < NEB) {
        int e = blk * 256 + t;
        if (e < NE) {
            unsigned d = (unsigned)edst[e];
            if (d < NT) {
                int slot = atomicAdd(&cnt[d], 1);
                if (slot < CAP) csr[d * CAP + slot] = (u16)esrc[e];
            }
        }
        return;
    }
    if (blk < NEB + CVB) {
        int gidx = (blk - NEB) * 256 + t;        // < 1,280,000
        int tile = gidx >> 10;                   // /1024 (16kk*64lane)
        int rem = gidx & 1023;
        int kk = rem >> 6, lane = rem & 63;
        int row = tile * 16 + (lane & 15);
        int colbase = kk * 32 + ((lane >> 4) << 3);
        float v[8];
        if (colbase + 7 < 500) {
            const float4* p = (const float4*)(train + (size_t)row * 500 + colbase);
            float4 x0 = p[0], x1 = p[1];
            v[0] = x0.x; v[1] = x0.y; v[2] = x0.z; v[3] = x0.w;
            v[4] = x1.x; v[5] = x1.y; v[6] = x1.z; v[7] = x1.w;
        } else {
#pragma unroll
            for (int j = 0; j < 8; ++j) {
                int c = colbase + j;
                v[j] = (c < 500) ? train[(size_t)row * 500 + c] : 0.f;
            }
        }
        u32 w[4];
#pragma unroll
        for (int p = 0; p < 4; ++p)
            w[p] = (u32)f2b(v[2 * p]) | ((u32)f2b(v[2 * p + 1]) << 16);
        *(uint4*)(AF + (((size_t)tile * 20 + kk) * 64 + lane) * 8) =
            make_uint4(w[0], w[1], w[2], w[3]);
        return;
    }
    // ---- weight pack ----
    int idx = (blk - NEB - CVB) * 256 + t;
    float v = 0.f;
    u16 *ph = 0, *pl = 0;
    int off = 0;
    if (idx < B1N) {
        int j = idx & 7, l = (idx >> 3) & 63, rest = idx >> 9;
        int g = rest & 7, kk = rest >> 3;
        int k = kk * 32 + ((l >> 4) << 3) + j, n = (g << 4) + (l & 15);
        if (k < 500) v = W1s[k * 128 + n];
        else if (k >= 512) v = W1n[(k - 512) * 128 + n];
        ph = B1h; pl = B1l; off = idx;
    } else if (idx < B1N + B2N) {
        int e = idx - B1N;
        int j = e & 7, l = (e >> 3) & 63, rest = e >> 9;
        int g = rest & 7, kk = rest >> 3;
        int k = kk * 32 + ((l >> 4) << 3) + j, n = (g << 4) + (l & 15);
        v = (k < 128) ? W2s[k * 128 + n] : W2n[(k - 128) * 128 + n];
        ph = B2h; pl = B2l; off = e;
    } else if (idx < B1N + B2N + B3N) {
        int e = idx - (B1N + B2N);
        int j = e & 7, l = (e >> 3) & 63, rest = e >> 9;
        int g = rest & 7, kk = rest >> 3;
        int k = kk * 32 + ((l >> 4) << 3) + j, n = (g << 4) + (l & 15);
        v = Wc1[k * 128 + n];
        ph = B3h; pl = B3l; off = e;
    } else if (idx < B1N + B2N + B3N + B4N) {
        int e = idx - (B1N + B2N + B3N);
        int j = e & 7, l = (e >> 3) & 63, kk = e >> 9;
        int k = kk * 32 + ((l >> 4) << 3) + j, n = l & 15;
        v = Wc2[k * 16 + n];
        ph = B4h; pl = B4l; off = e;
    }
    if (ph) {
        u16 hi = f2b(v);
        u16 lo = f2b(v - b2f(hi));
        ph[off] = hi;
        pl[off] = lo;
    }
}

// ---- gather-mean -> AF kk16..19 (hi) + AFL kk0..3 (lo), fragment order ----
// One block per tile (16 dst rows). Thread t: kkg = t>>6, flane = t&63.
__global__ __launch_bounds__(256) void k_gather(const float* __restrict__ gene,
                                                const int* __restrict__ cnt,
                                                const u16* __restrict__ csr,
                                                u16* __restrict__ AF,
                                                u16* __restrict__ AFL) {
    __shared__ u16 scsr[16 * CAP];
    __shared__ int scnt[16];
    int tile = blockIdx.x, t = threadIdx.x;
    int d0 = tile * 16;
    if (t < 16) {
        int c = cnt[d0 + t];
        scnt[t] = c > CAP ? CAP : c;
    }
    for (int i = t; i < 16 * CAP; i += 256) scsr[i] = csr[(size_t)(d0 + i / CAP) * CAP + i % CAP];
    __syncthreads();

    int kkg = t >> 6, flane = t & 63;
    int m = flane & 15, q = flane >> 4;
    int colbase = kkg * 32 + q * 8;   // 0..127 within agg dim
    int c = scnt[m];
    const u16* row = scsr + m * CAP;
    float a[8];
#pragma unroll
    for (int j = 0; j < 8; ++j) a[j] = 0.f;
    for (int j = 0; j < c; ++j) {
        int s = row[j];
        const float4* gp = (const float4*)(gene + (size_t)s * 128 + colbase);
        float4 x0 = gp[0], x1 = gp[1];
        a[0] += x0.x; a[1] += x0.y; a[2] += x0.z; a[3] += x0.w;
        a[4] += x1.x; a[5] += x1.y; a[6] += x1.z; a[7] += x1.w;
    }
    float inv = (c > 0) ? 1.f / (float)c : 0.f;
    u32 wh[4], wl[4];
#pragma unroll
    for (int p = 0; p < 4; ++p) {
        float x = a[2 * p] * inv, y = a[2 * p + 1] * inv;
        u16 hx = f2b(x), hy = f2b(y);
        u16 lx = f2b(x - b2f(hx)), ly = f2b(y - b2f(hy));
        wh[p] = (u32)hx | ((u32)hy << 16);
        wl[p] = (u32)lx | ((u32)ly << 16);
    }
    *(uint4*)(AF + (((size_t)tile * 20 + 16 + kkg) * 64 + flane) * 8) =
        make_uint4(wh[0], wh[1], wh[2], wh[3]);
    *(uint4*)(AFL + (((size_t)tile * 4 + kkg) * 64 + flane) * 8) =
        make_uint4(wl[0], wl[1], wl[2], wl[3]);
}

// ---- fused 4-layer MFMA kernel, A+B streamed from global (frag order) -----
// Block: 512 thr (8 waves), 32 rows (2 tiles). wave: rt=wave&1, cw=wave>>1.
__global__ __launch_bounds__(512) void k_mega(
    const u16* __restrict__ AF, const u16* __restrict__ AFL,
    const u16* __restrict__ B1h, const u16* __restrict__ B1l,
    const u16* __restrict__ B2h, const u16* __restrict__ B2l,
    const u16* __restrict__ B3h, const u16* __restrict__ B3l,
    const u16* __restrict__ B4h, const u16* __restrict__ B4l,
    const float* __restrict__ b1, const float* __restrict__ b2,
    const float* __restrict__ bc1, const float* __restrict__ bc2,
    float* __restrict__ out) {
    __shared__ __align__(16) u16 S1h[32 * 136], S1l[32 * 136];
    __shared__ __align__(16) u16 S2h[32 * 136], S2l[32 * 136];
    int t = threadIdx.x;
    int lane = t & 63, wave = t >> 6;
    int rt = wave & 1, cw = wave >> 1;  // cw 0..3
    int g0 = cw * 2;
    int m = lane & 15, q = lane >> 4, n16 = lane & 15;
    int row0 = blockIdx.x * 32;
    int tile = blockIdx.x * 2 + rt;

    const u16* aBase = AF + (((size_t)tile * 20) * 64 + lane) * 8;   // +512/kk
    const u16* alBase = AFL + (((size_t)tile * 4) * 64 + lane) * 8;  // +512/kk
    int hrow = (rt * 16 + m) * 136 + q * 8;
    int crow = rt * 16 + q * 4;
    const f32x4 z4 = {0.f, 0.f, 0.f, 0.f};
    f32x4 acc0 = z4, acc1 = z4;

    // ---- layer1: K=640 (train hi-only kk 0..15; agg hi+lo kk 16..19) ----
#pragma unroll 4
    for (int kk = 0; kk < 16; ++kk) {
        bf16x8 ah = *(const bf16x8*)(aBase + kk * 512);
        size_t bo0 = ((size_t)(kk * 8 + g0) * 64 + lane) * 8;
        bf16x8 bh0 = *(const bf16x8*)(B1h + bo0);
        bf16x8 bl0 = *(const bf16x8*)(B1l + bo0);
        bf16x8 bh1 = *(const bf16x8*)(B1h + bo0 + 512);
        bf16x8 bl1 = *(const bf16x8*)(B1l + bo0 + 512);
        acc0 = __builtin_amdgcn_mfma_f32_16x16x32_bf16(ah, bh0, acc0, 0, 0, 0);
        acc0 = __builtin_amdgcn_mfma_f32_16x16x32_bf16(ah, bl0, acc0, 0, 0, 0);
        acc1 = __builtin_amdgcn_mfma_f32_16x16x32_bf16(ah, bh1, acc1, 0, 0, 0);
        acc1 = __builtin_amdgcn_mfma_f32_16x16x32_bf16(ah, bl1, acc1, 0, 0, 0);
    }
#pragma unroll
    for (int kk = 16; kk < 20; ++kk) {
        bf16x8 ah = *(const bf16x8*)(aBase + kk * 512);
        bf16x8 al = *(const bf16x8*)(alBase + (kk - 16) * 512);
        size_t bo0 = ((size_t)(kk * 8 + g0) * 64 + lane) * 8;
        bf16x8 bh0 = *(const bf16x8*)(B1h + bo0);
        bf16x8 bl0 = *(const bf16x8*)(B1l + bo0);
        bf16x8 bh1 = *(const bf16x8*)(B1h + bo0 + 512);
        bf16x8 bl1 = *(const bf16x8*)(B1l + bo0 + 512);
        acc0 = __builtin_amdgcn_mfma_f32_16x16x32_bf16(ah, bh0, acc0, 0, 0, 0);
        acc0 = __builtin_amdgcn_mfma_f32_16x16x32_bf16(ah, bl0, acc0, 0, 0, 0);
        acc0 = __builtin_amdgcn_mfma_f32_16x16x32_bf16(al, bh0, acc0, 0, 0, 0);
        acc1 = __builtin_amdgcn_mfma_f32_16x16x32_bf16(ah, bh1, acc1, 0, 0, 0);
        acc1 = __builtin_amdgcn_mfma_f32_16x16x32_bf16(ah, bl1, acc1, 0, 0, 0);
        acc1 = __builtin_amdgcn_mfma_f32_16x16x32_bf16(al, bh1, acc1, 0, 0, 0);
    }
    {
        int n0 = g0 * 16 + n16, n1 = n0 + 16;
        float bias0 = b1[n0], bias1 = b1[n1];
#pragma unroll
        for (int rg = 0; rg < 4; ++rg) {
            float v0 = acc0[rg] + bias0; v0 = v0 > 0.f ? v0 : 0.f;
            float v1 = acc1[rg] + bias1; v1 = v1 > 0.f ? v1 : 0.f;
            u16 h0 = f2b(v0), h1v = f2b(v1);
            int ix = (crow + rg) * 136;
            S1h[ix + n0] = h0; S1l[ix + n0] = f2b(v0 - b2f(h0));
            S1h[ix + n1] = h1v; S1l[ix + n1] = f2b(v1 - b2f(h1v));
        }
    }
    __syncthreads();

    // ---- layer2: K=256 (h1 kk 0..3 LDS; agg kk 4..7 global frag) ----
    acc0 = z4; acc1 = z4;
#pragma unroll
    for (int kk = 0; kk < 8; ++kk) {
        bf16x8 ah, al;
        if (kk < 4) {
            ah = *(const bf16x8*)(S1h + hrow + kk * 32);
            al = *(const bf16x8*)(S1l + hrow + kk * 32);
        } else {
            ah = *(const bf16x8*)(aBase + (16 + kk - 4) * 512);
            al = *(const bf16x8*)(alBase + (kk - 4) * 512);
        }
        size_t bo0 = ((size_t)(kk * 8 + g0) * 64 + lane) * 8;
        bf16x8 bh0 = *(const bf16x8*)(B2h + bo0);
        bf16x8 bl0 = *(const bf16x8*)(B2l + bo0);
        bf16x8 bh1 = *(const bf16x8*)(B2h + bo0 + 512);
        bf16x8 bl1 = *(const bf16x8*)(B2l + bo0 + 512);
        acc0 = __builtin_amdgcn_mfma_f32_16x16x32_bf16(ah, bh0, acc0, 0, 0, 0);
        acc0 = __builtin_amdgcn_mfma_f32_16x16x32_bf16(ah, bl0, acc0, 0, 0, 0);
        acc0 = __builtin_amdgcn_mfma_f32_16x16x32_bf16(al, bh0, acc0, 0, 0, 0);
        acc1 = __builtin_amdgcn_mfma_f32_16x16x32_bf16(ah, bh1, acc1, 0, 0, 0);
        acc1 = __builtin_amdgcn_mfma_f32_16x16x32_bf16(ah, bl1, acc1, 0, 0, 0);
        acc1 = __builtin_amdgcn_mfma_f32_16x16x32_bf16(al, bh1, acc1, 0, 0, 0);
    }
    {
        int n0 = g0 * 16 + n16, n1 = n0 + 16;
        float bias0 = b2[n0], bias1 = b2[n1];
#pragma unroll
        for (int rg = 0; rg < 4; ++rg) {
            float v0 = acc0[rg] + bias0; v0 = v0 > 0.f ? v0 : 0.f;
            float v1 = acc1[rg] + bias1; v1 = v1 > 0.f ? v1 : 0.f;
            u16 h0 = f2b(v0), h1v = f2b(v1);
            int ix = (crow + rg) * 136;
            S2h[ix + n0] = h0; S2l[ix + n0] = f2b(v0 - b2f(h0));
            S2h[ix + n1] = h1v; S2l[ix + n1] = f2b(v1 - b2f(h1v));
        }
    }
    __syncthreads();

    // ---- layer3: K=128 (h2 LDS) -> S1 ----
    acc0 = z4; acc1 = z4;
#pragma unroll
    for (int kk = 0; kk < 4; ++kk) {
        bf16x8 ah = *(const bf16x8*)(S2h + hrow + kk * 32);
        bf16x8 al = *(const bf16x8*)(S2l + hrow + kk * 32);
        size_t bo0 = ((size_t)(kk * 8 + g0) * 64 + lane) * 8;
        bf16x8 bh0 = *(const bf16x8*)(B3h + bo0);
        bf16x8 bl0 = *(const bf16x8*)(B3l + bo0);
        bf16x8 bh1 = *(const bf16x8*)(B3h + bo0 + 512);
        bf16x8 bl1 = *(const bf16x8*)(B3l + bo0 + 512);
        acc0 = __builtin_amdgcn_mfma_f32_16x16x32_bf16(ah, bh0, acc0, 0, 0, 0);
        acc0 = __builtin_amdgcn_mfma_f32_16x16x32_bf16(ah, bl0, acc0, 0, 0, 0);
        acc0 = __builtin_amdgcn_mfma_f32_16x16x32_bf16(al, bh0, acc0, 0, 0, 0);
        acc1 = __builtin_amdgcn_mfma_f32_16x16x32_bf16(ah, bh1, acc1, 0, 0, 0);
        acc1 = __builtin_amdgcn_mfma_f32_16x16x32_bf16(ah, bl1, acc1, 0, 0, 0);
        acc1 = __builtin_amdgcn_mfma_f32_16x16x32_bf16(al, bh1, acc1, 0, 0, 0);
    }
    {
        int n0 = g0 * 16 + n16, n1 = n0 + 16;
        float bias0 = bc1[n0], bias1 = bc1[n1];
#pragma unroll
        for (int rg = 0; rg < 4; ++rg) {
            float v0 = acc0[rg] + bias0; v0 = v0 > 0.f ? v0 : 0.f;
            float v1 = acc1[rg] + bias1; v1 = v1 > 0.f ? v1 : 0.f;
            u16 h0 = f2b(v0), h1v = f2b(v1);
            int ix = (crow + rg) * 136;
            S1h[ix + n0] = h0; S1l[ix + n0] = f2b(v0 - b2f(h0));
            S1h[ix + n1] = h1v; S1l[ix + n1] = f2b(v1 - b2f(h1v));
        }
    }
    __syncthreads();

    // ---- layer4: K=128, N=16 (cw==0 waves only; rt covers both tiles) ----
    if (cw == 0) {
        f32x4 a4 = z4;
#pragma unroll
        for (int kk = 0; kk < 4; ++kk) {
            bf16x8 ah = *(const bf16x8*)(S1h + hrow + kk * 32);
            bf16x8 al = *(const bf16x8*)(S1l + hrow + kk * 32);
            size_t bo = ((size_t)kk * 64 + lane) * 8;
            bf16x8 bh = *(const bf16x8*)(B4h + bo);
            bf16x8 bl = *(const bf16x8*)(B4l + bo);
            a4 = __builtin_amdgcn_mfma_f32_16x16x32_bf16(ah, bh, a4, 0, 0, 0);
            a4 = __builtin_amdgcn_mfma_f32_16x16x32_bf16(ah, bl, a4, 0, 0, 0);
            a4 = __builtin_amdgcn_mfma_f32_16x16x32_bf16(al, bh, a4, 0, 0, 0);
        }
        float bias = bc2[n16];
#pragma unroll
        for (int rg = 0; rg < 4; ++rg)
            out[(size_t)(row0 + crow + rg) * NCLS + n16] = a4[rg] + bias;
    }
}

extern "C" void kernel_launch(void* const* d_in, const int* in_sizes, int n_in,
                              void* d_out, int out_size, void* d_ws, size_t ws_size,
                              hipStream_t stream) {
    const float* gene = (const float*)d_in[0];
    const float* train = (const float*)d_in[1];
    const int* esrc = (const int*)d_in[2];
    const int* edst = (const int*)d_in[3];

    char* ws = (char*)d_ws;
    int* cnt = (int*)(ws + 0);              //    80000
    u16* csr = (u16*)(ws + 80000);          //  3840000
    u16* AF = (u16*)(ws + 3920000);         // 25600000 (1250*20*64*8 u16)
    u16* AFL = (u16*)(ws + 29520000);       //  5120000 (1250*4*64*8 u16)
    u16* B1h = (u16*)(ws + 34640000);       //   163840
    u16* B1l = (u16*)(ws + 34803840);       //   163840
    u16* B2h = (u16*)(ws + 34967680);       //    65536
    u16* B2l = (u16*)(ws + 35033216);       //    65536
    u16* B3h = (u16*)(ws + 35098752);       //    32768
    u16* B3l = (u16*)(ws + 35131520);       //    32768
    u16* B4h = (u16*)(ws + 35164288);       //     4096
    u16* B4l = (u16*)(ws + 35168384);       //     4096
    // total 35,172,480 B (same envelope as round 7)

    hipMemsetAsync(cnt, 0, NT * sizeof(int), stream);
    k_prep<<<NEB + CVB + PKB, 256, 0, stream>>>(
        esrc, edst, cnt, csr, train, AF,
        (const float*)d_in[4], (const float*)d_in[5], (const float*)d_in[7],
        (const float*)d_in[8], (const float*)d_in[10], (const float*)d_in[12],
        B1h, B1l, B2h, B2l, B3h, B3l, B4h, B4l);
    k_gather<<<NTILE, 256, 0, stream>>>(gene, cnt, csr, AF, AFL);
    k_mega<<<NT / 32, 512, 0, stream>>>(
        AF, AFL, B1h, B1l, B2h, B2l, B3h, B3l, B4h, B4l,
        (const float*)d_in[6], (const float*)d_in[9], (const float*)d_in[11],
        (const float*)d_in[13], (float*)d_out);
}

// Round 9
// 186.214 us; speedup vs baseline: 1.1944x; 1.1944x over previous
//
#include <hip/hip_runtime.h>

// WordSAGE on MI355X — fp32 in/out. Round-9 structure (3 kernels + memset):
//   k_edges: padded-CSR fillpad (atomics + u16 scatter), one edge pass
//   k_conv : per-tile LDS-staged train->AF (coalesced read AND write)
//            + gene->GH bf16-hi + weight pack  (branch by blockIdx)
//   k_mega : phase0 = per-block gather-mean from GH (L2-resident) into LDS,
//            then fused 4-layer split-bf16 MFMA (A from AF frag-order global,
//            agg/h tiles in LDS). 52KB LDS -> 3 blocks/CU.
// Precision: weights/agg/h split hi+lo bf16; train & gene hi-only.

#define NG 2500
#define NT 20000
#define NE 640000
#define NCLS 16
#define CAP 96
#define NTILE 1250   // NT/16

typedef unsigned short u16;
typedef unsigned int u32;

typedef float f32x4 __attribute__((ext_vector_type(4)));
typedef __bf16 bf16x8 __attribute__((ext_vector_type(8)));

__device__ __forceinline__ float b2f(u16 u) { return __uint_as_float(((u32)u) << 16); }
__device__ __forceinline__ float blo(u32 p) { return __uint_as_float(p << 16); }
__device__ __forceinline__ float bhi(u32 p) { return __uint_as_float(p & 0xffff0000u); }
__device__ __forceinline__ u16 f2b(float f) {  // RNE fp32->bf16
    u32 u = __float_as_uint(f);
    return (u16)((u + 0x7fffu + ((u >> 16) & 1u)) >> 16);
}

// ---- B-fragment pack sizes ------------------------------------------------
#define B1N 81920   // K=640: train k 0..499, zero 500..511, agg 512..639; N=128
#define B2N 32768   // K=256: h1 (W2s) 0..127, agg (W2n) 128..255; N=128
#define B3N 16384   // K=128 Wc1, N=128
#define B4N 2048    // K=128 Wc2, N=16
#define CVB NTILE   // 1250 tile-convert blocks
#define GNB 625     // gene-convert blocks (2500*128/2 u32 / 256)
#define PKB 520     // pack blocks

// ---- edge fillpad ---------------------------------------------------------
__global__ __launch_bounds__(256) void k_edges(const int* __restrict__ esrc,
                                               const int* __restrict__ edst,
                                               int* __restrict__ cnt,
                                               u16* __restrict__ csr) {
    int e = blockIdx.x * 256 + threadIdx.x;
    if (e < NE) {
        unsigned d = (unsigned)edst[e];
        if (d < NT) {
            int slot = atomicAdd(&cnt[d], 1);
            if (slot < CAP) csr[(size_t)d * CAP + slot] = (u16)esrc[e];
        }
    }
}

// ---- conv: train->AF (LDS-staged, coalesced) | gene->GH | weight pack -----
__global__ __launch_bounds__(256) void k_conv(
    const float* __restrict__ train, const float* __restrict__ gene,
    u16* __restrict__ AF, u32* __restrict__ GH32,
    const float* __restrict__ W1n, const float* __restrict__ W1s,
    const float* __restrict__ W2n, const float* __restrict__ W2s,
    const float* __restrict__ Wc1, const float* __restrict__ Wc2,
    u16* __restrict__ B1h, u16* __restrict__ B1l,
    u16* __restrict__ B2h, u16* __restrict__ B2l,
    u16* __restrict__ B3h, u16* __restrict__ B3l,
    u16* __restrict__ B4h, u16* __restrict__ B4l) {
    int blk = blockIdx.x, t = threadIdx.x;
    if (blk < CVB) {
        // one tile = 16 train rows -> AF fragment order
        __shared__ __align__(16) u16 L[16 * 520];
        u32* L32 = (u32*)L;
        int tile = blk;
        for (int i = t; i < 160; i += 256) {  // zero cols 500..519
            int r = i / 10, c = i - r * 10;
            L32[r * 260 + 250 + c] = 0;
        }
        for (int i = t; i < 2000; i += 256) { // 16 rows x 125 float4, coalesced
            int r = i / 125, c4 = i - r * 125;
            float4 v = *(const float4*)(train + (size_t)(tile * 16 + r) * 500 + c4 * 4);
            int base = r * 260 + c4 * 2;
            L32[base] = (u32)f2b(v.x) | ((u32)f2b(v.y) << 16);
            L32[base + 1] = (u32)f2b(v.z) | ((u32)f2b(v.w) << 16);
        }
        __syncthreads();
#pragma unroll
        for (int it = 0; it < 4; ++it) {      // 16 kk x 64 lanes, coalesced out
            int slot = t + it * 256;
            int kk = slot >> 6, lane = slot & 63;
            int m = lane & 15, q = lane >> 4;
            uint4 v = *(const uint4*)(L + m * 520 + kk * 32 + q * 8);
            *(uint4*)(AF + (((size_t)tile * 16 + kk) * 64 + lane) * 8) = v;
        }
        return;
    }
    if (blk < CVB + GNB) {
        int idx = (blk - CVB) * 256 + t;      // < 160000
        float2 v = ((const float2*)gene)[idx];
        GH32[idx] = (u32)f2b(v.x) | ((u32)f2b(v.y) << 16);
        return;
    }
    // ---- weight pack (split hi/lo, B-fragment order) ----
    int idx = (blk - CVB - GNB) * 256 + t;
    float v = 0.f;
    u16 *ph = 0, *pl = 0;
    int off = 0;
    if (idx < B1N) {
        int j = idx & 7, l = (idx >> 3) & 63, rest = idx >> 9;
        int g = rest & 7, kk = rest >> 3;
        int k = kk * 32 + ((l >> 4) << 3) + j, n = (g << 4) + (l & 15);
        if (k < 500) v = W1s[k * 128 + n];
        else if (k >= 512) v = W1n[(k - 512) * 128 + n];
        ph = B1h; pl = B1l; off = idx;
    } else if (idx < B1N + B2N) {
        int e = idx - B1N;
        int j = e & 7, l = (e >> 3) & 63, rest = e >> 9;
        int g = rest & 7, kk = rest >> 3;
        int k = kk * 32 + ((l >> 4) << 3) + j, n = (g << 4) + (l & 15);
        v = (k < 128) ? W2s[k * 128 + n] : W2n[(k - 128) * 128 + n];
        ph = B2h; pl = B2l; off = e;
    } else if (idx < B1N + B2N + B3N) {
        int e = idx - (B1N + B2N);
        int j = e & 7, l = (e >> 3) & 63, rest = e >> 9;
        int g = rest & 7, kk = rest >> 3;
        int k = kk * 32 + ((l >> 4) << 3) + j, n = (g << 4) + (l & 15);
        v = Wc1[k * 128 + n];
        ph = B3h; pl = B3l; off = e;
    } else if (idx < B1N + B2N + B3N + B4N) {
        int e = idx - (B1N + B2N + B3N);
        int j = e & 7, l = (e >> 3) & 63, kk = e >> 9;
        int k = kk * 32 + ((l >> 4) << 3) + j, n = l & 15;
        v = Wc2[k * 16 + n];
        ph = B4h; pl = B4l; off = e;
    }
    if (ph) {
        u16 hi = f2b(v);
        u16 lo = f2b(v - b2f(hi));
        ph[off] = hi;
        pl[off] = lo;
    }
}

// ---- fused gather + 4-layer MFMA ------------------------------------------
// Block: 512 thr (8 waves), 32 rows. wave: rt=wave&1, cw=wave>>1 (2 col-grps).
__global__ __launch_bounds__(512) void k_mega(
    const int* __restrict__ cnt, const u16* __restrict__ csr,
    const u16* __restrict__ GH, const u16* __restrict__ AF,
    const u16* __restrict__ B1h, const u16* __restrict__ B1l,
    const u16* __restrict__ B2h, const u16* __restrict__ B2l,
    const u16* __restrict__ B3h, const u16* __restrict__ B3l,
    const u16* __restrict__ B4h, const u16* __restrict__ B4l,
    const float* __restrict__ b1, const float* __restrict__ b2,
    const float* __restrict__ bc1, const float* __restrict__ bc2,
    float* __restrict__ out) {
    __shared__ __align__(16) u16 SAGh[32 * 136], SAGl[32 * 136];
    __shared__ __align__(16) u16 S1h[32 * 136], S1l[32 * 136];
    __shared__ __align__(16) u16 S2h[32 * 136], S2l[32 * 136];
    int t = threadIdx.x;
    int row0 = blockIdx.x * 32;

    // ---- phase 0: gather-mean of gene-hi into SAG (agg hi/lo) ----
    {
        int r = t >> 4, cg = t & 15;           // row 0..31, col-group 0..15
        int d = row0 + r;
        int ctrue = cnt[d];
        int c = ctrue > CAP ? CAP : ctrue;
        const u16* crow = csr + (size_t)d * CAP;
        float a[8];
#pragma unroll
        for (int p = 0; p < 8; ++p) a[p] = 0.f;
        int j = 0;
        for (; j + 1 < c; j += 2) {
            int s0 = crow[j], s1 = crow[j + 1];
            uint4 p0 = *(const uint4*)(GH + (size_t)s0 * 128 + cg * 8);
            uint4 p1 = *(const uint4*)(GH + (size_t)s1 * 128 + cg * 8);
            a[0] += blo(p0.x); a[1] += bhi(p0.x);
            a[2] += blo(p0.y); a[3] += bhi(p0.y);
            a[4] += blo(p0.z); a[5] += bhi(p0.z);
            a[6] += blo(p0.w); a[7] += bhi(p0.w);
            a[0] += blo(p1.x); a[1] += bhi(p1.x);
            a[2] += blo(p1.y); a[3] += bhi(p1.y);
            a[4] += blo(p1.z); a[5] += bhi(p1.z);
            a[6] += blo(p1.w); a[7] += bhi(p1.w);
        }
        if (j < c) {
            int s = crow[j];
            uint4 p0 = *(const uint4*)(GH + (size_t)s * 128 + cg * 8);
            a[0] += blo(p0.x); a[1] += bhi(p0.x);
            a[2] += blo(p0.y); a[3] += bhi(p0.y);
            a[4] += blo(p0.z); a[5] += bhi(p0.z);
            a[6] += blo(p0.w); a[7] += bhi(p0.w);
        }
        float inv = (ctrue > 0) ? 1.f / (float)ctrue : 0.f;
        int base = (r * 136 + cg * 8) >> 1;    // u32 index (even)
        u32* SH = (u32*)SAGh;
        u32* SL = (u32*)SAGl;
#pragma unroll
        for (int p = 0; p < 4; ++p) {
            float x = a[2 * p] * inv, y = a[2 * p + 1] * inv;
            u16 hx = f2b(x), hy = f2b(y);
            SH[base + p] = (u32)hx | ((u32)hy << 16);
            SL[base + p] = (u32)f2b(x - b2f(hx)) | ((u32)f2b(y - b2f(hy)) << 16);
        }
    }
    __syncthreads();

    int lane = t & 63, wave = t >> 6;
    int rt = wave & 1, cw = wave >> 1;  // cw 0..3
    int g0 = cw * 2;
    int m = lane & 15, q = lane >> 4, n16 = lane & 15;
    int tile = blockIdx.x * 2 + rt;

    const u16* aBase = AF + (((size_t)tile * 16) * 64 + lane) * 8;  // +512/kk
    int hrow = (rt * 16 + m) * 136 + q * 8;
    int crow = rt * 16 + q * 4;
    const f32x4 z4 = {0.f, 0.f, 0.f, 0.f};
    f32x4 acc0 = z4, acc1 = z4;

    // ---- layer1: K=640 (train hi kk0..15 global; agg hi+lo kk16..19 LDS) ----
#pragma unroll 4
    for (int kk = 0; kk < 16; ++kk) {
        bf16x8 ah = *(const bf16x8*)(aBase + kk * 512);
        size_t bo0 = ((size_t)(kk * 8 + g0) * 64 + lane) * 8;
        bf16x8 bh0 = *(const bf16x8*)(B1h + bo0);
        bf16x8 bl0 = *(const bf16x8*)(B1l + bo0);
        bf16x8 bh1 = *(const bf16x8*)(B1h + bo0 + 512);
        bf16x8 bl1 = *(const bf16x8*)(B1l + bo0 + 512);
        acc0 = __builtin_amdgcn_mfma_f32_16x16x32_bf16(ah, bh0, acc0, 0, 0, 0);
        acc0 = __builtin_amdgcn_mfma_f32_16x16x32_bf16(ah, bl0, acc0, 0, 0, 0);
        acc1 = __builtin_amdgcn_mfma_f32_16x16x32_bf16(ah, bh1, acc1, 0, 0, 0);
        acc1 = __builtin_amdgcn_mfma_f32_16x16x32_bf16(ah, bl1, acc1, 0, 0, 0);
    }
#pragma unroll
    for (int kk = 16; kk < 20; ++kk) {
        bf16x8 ah = *(const bf16x8*)(SAGh + hrow + (kk - 16) * 32);
        bf16x8 al = *(const bf16x8*)(SAGl + hrow + (kk - 16) * 32);
        size_t bo0 = ((size_t)(kk * 8 + g0) * 64 + lane) * 8;
        bf16x8 bh0 = *(const bf16x8*)(B1h + bo0);
        bf16x8 bl0 = *(const bf16x8*)(B1l + bo0);
        bf16x8 bh1 = *(const bf16x8*)(B1h + bo0 + 512);
        bf16x8 bl1 = *(const bf16x8*)(B1l + bo0 + 512);
        acc0 = __builtin_amdgcn_mfma_f32_16x16x32_bf16(ah, bh0, acc0, 0, 0, 0);
        acc0 = __builtin_amdgcn_mfma_f32_16x16x32_bf16(ah, bl0, acc0, 0, 0, 0);
        acc0 = __builtin_amdgcn_mfma_f32_16x16x32_bf16(al, bh0, acc0, 0, 0, 0);
        acc1 = __builtin_amdgcn_mfma_f32_16x16x32_bf16(ah, bh1, acc1, 0, 0, 0);
        acc1 = __builtin_amdgcn_mfma_f32_16x16x32_bf16(ah, bl1, acc1, 0, 0, 0);
        acc1 = __builtin_amdgcn_mfma_f32_16x16x32_bf16(al, bh1, acc1, 0, 0, 0);
    }
    {
        int n0 = g0 * 16 + n16, n1 = n0 + 16;
        float bias0 = b1[n0], bias1 = b1[n1];
#pragma unroll
        for (int rg = 0; rg < 4; ++rg) {
            float v0 = acc0[rg] + bias0; v0 = v0 > 0.f ? v0 : 0.f;
            float v1 = acc1[rg] + bias1; v1 = v1 > 0.f ? v1 : 0.f;
            u16 h0 = f2b(v0), h1v = f2b(v1);
            int ix = (crow + rg) * 136;
            S1h[ix + n0] = h0; S1l[ix + n0] = f2b(v0 - b2f(h0));
            S1h[ix + n1] = h1v; S1l[ix + n1] = f2b(v1 - b2f(h1v));
        }
    }
    __syncthreads();

    // ---- layer2: K=256 (h1 kk0..3 LDS; agg kk4..7 LDS) ----
    acc0 = z4; acc1 = z4;
#pragma unroll
    for (int kk = 0; kk < 8; ++kk) {
        bf16x8 ah, al;
        if (kk < 4) {
            ah = *(const bf16x8*)(S1h + hrow + kk * 32);
            al = *(const bf16x8*)(S1l + hrow + kk * 32);
        } else {
            ah = *(const bf16x8*)(SAGh + hrow + (kk - 4) * 32);
            al = *(const bf16x8*)(SAGl + hrow + (kk - 4) * 32);
        }
        size_t bo0 = ((size_t)(kk * 8 + g0) * 64 + lane) * 8;
        bf16x8 bh0 = *(const bf16x8*)(B2h + bo0);
        bf16x8 bl0 = *(const bf16x8*)(B2l + bo0);
        bf16x8 bh1 = *(const bf16x8*)(B2h + bo0 + 512);
        bf16x8 bl1 = *(const bf16x8*)(B2l + bo0 + 512);
        acc0 = __builtin_amdgcn_mfma_f32_16x16x32_bf16(ah, bh0, acc0, 0, 0, 0);
        acc0 = __builtin_amdgcn_mfma_f32_16x16x32_bf16(ah, bl0, acc0, 0, 0, 0);
        acc0 = __builtin_amdgcn_mfma_f32_16x16x32_bf16(al, bh0, acc0, 0, 0, 0);
        acc1 = __builtin_amdgcn_mfma_f32_16x16x32_bf16(ah, bh1, acc1, 0, 0, 0);
        acc1 = __builtin_amdgcn_mfma_f32_16x16x32_bf16(ah, bl1, acc1, 0, 0, 0);
        acc1 = __builtin_amdgcn_mfma_f32_16x16x32_bf16(al, bh1, acc1, 0, 0, 0);
    }
    {
        int n0 = g0 * 16 + n16, n1 = n0 + 16;
        float bias0 = b2[n0], bias1 = b2[n1];
#pragma unroll
        for (int rg = 0; rg < 4; ++rg) {
            float v0 = acc0[rg] + bias0; v0 = v0 > 0.f ? v0 : 0.f;
            float v1 = acc1[rg] + bias1; v1 = v1 > 0.f ? v1 : 0.f;
            u16 h0 = f2b(v0), h1v = f2b(v1);
            int ix = (crow + rg) * 136;
            S2h[ix + n0] = h0; S2l[ix + n0] = f2b(v0 - b2f(h0));
            S2h[ix + n1] = h1v; S2l[ix + n1] = f2b(v1 - b2f(h1v));
        }
    }
    __syncthreads();

    // ---- layer3: K=128 (h2 LDS) -> S1 ----
    acc0 = z4; acc1 = z4;
#pragma unroll
    for (int kk = 0; kk < 4; ++kk) {
        bf16x8 ah = *(const bf16x8*)(S2h + hrow + kk * 32);
        bf16x8 al = *(const bf16x8*)(S2l + hrow + kk * 32);
        size_t bo0 = ((size_t)(kk * 8 + g0) * 64 + lane) * 8;
        bf16x8 bh0 = *(const bf16x8*)(B3h + bo0);
        bf16x8 bl0 = *(const bf16x8*)(B3l + bo0);
        bf16x8 bh1 = *(const bf16x8*)(B3h + bo0 + 512);
        bf16x8 bl1 = *(const bf16x8*)(B3l + bo0 + 512);
        acc0 = __builtin_amdgcn_mfma_f32_16x16x32_bf16(ah, bh0, acc0, 0, 0, 0);
        acc0 = __builtin_amdgcn_mfma_f32_16x16x32_bf16(ah, bl0, acc0, 0, 0, 0);
        acc0 = __builtin_amdgcn_mfma_f32_16x16x32_bf16(al, bh0, acc0, 0, 0, 0);
        acc1 = __builtin_amdgcn_mfma_f32_16x16x32_bf16(ah, bh1, acc1, 0, 0, 0);
        acc1 = __builtin_amdgcn_mfma_f32_16x16x32_bf16(ah, bl1, acc1, 0, 0, 0);
        acc1 = __builtin_amdgcn_mfma_f32_16x16x32_bf16(al, bh1, acc1, 0, 0, 0);
    }
    {
        int n0 = g0 * 16 + n16, n1 = n0 + 16;
        float bias0 = bc1[n0], bias1 = bc1[n1];
#pragma unroll
        for (int rg = 0; rg < 4; ++rg) {
            float v0 = acc0[rg] + bias0; v0 = v0 > 0.f ? v0 : 0.f;
            float v1 = acc1[rg] + bias1; v1 = v1 > 0.f ? v1 : 0.f;
            u16 h0 = f2b(v0), h1v = f2b(v1);
            int ix = (crow + rg) * 136;
            S1h[ix + n0] = h0; S1l[ix + n0] = f2b(v0 - b2f(h0));
            S1h[ix + n1] = h1v; S1l[ix + n1] = f2b(v1 - b2f(h1v));
        }
    }
    __syncthreads();

    // ---- layer4: K=128, N=16 (cw==0 waves only) ----
    if (cw == 0) {
        f32x4 a4 = z4;
#pragma unroll
        for (int kk = 0; kk < 4; ++kk) {
            bf16x8 ah = *(const bf16x8*)(S1h + hrow + kk * 32);
            bf16x8 al = *(const bf16x8*)(S1l + hrow + kk * 32);
            size_t bo = ((size_t)kk * 64 + lane) * 8;
            bf16x8 bh = *(const bf16x8*)(B4h + bo);
            bf16x8 bl = *(const bf16x8*)(B4l + bo);
            a4 = __builtin_amdgcn_mfma_f32_16x16x32_bf16(ah, bh, a4, 0, 0, 0);
            a4 = __builtin_amdgcn_mfma_f32_16x16x32_bf16(ah, bl, a4, 0, 0, 0);
            a4 = __builtin_amdgcn_mfma_f32_16x16x32_bf16(al, bh, a4, 0, 0, 0);
        }
        float bias = bc2[n16];
#pragma unroll
        for (int rg = 0; rg < 4; ++rg)
            out[(size_t)(row0 + crow + rg) * NCLS + n16] = a4[rg] + bias;
    }
}

extern "C" void kernel_launch(void* const* d_in, const int* in_sizes, int n_in,
                              void* d_out, int out_size, void* d_ws, size_t ws_size,
                              hipStream_t stream) {
    const float* gene = (const float*)d_in[0];
    const float* train = (const float*)d_in[1];
    const int* esrc = (const int*)d_in[2];
    const int* edst = (const int*)d_in[3];

    char* ws = (char*)d_ws;
    int* cnt = (int*)(ws + 0);              //    80000
    u16* csr = (u16*)(ws + 80000);          //  3840000
    u16* AF = (u16*)(ws + 3920000);         // 20480000 (1250*16*64*8 u16)
    u16* GH = (u16*)(ws + 24400000);        //   640000 (2500*128 u16)
    u16* B1h = (u16*)(ws + 25040000);       //   163840
    u16* B1l = (u16*)(ws + 25203840);       //   163840
    u16* B2h = (u16*)(ws + 25367680);       //    65536
    u16* B2l = (u16*)(ws + 25433216);       //    65536
    u16* B3h = (u16*)(ws + 25498752);       //    32768
    u16* B3l = (u16*)(ws + 25531520);       //    32768
    u16* B4h = (u16*)(ws + 25564288);       //     4096
    u16* B4l = (u16*)(ws + 25568384);       //     4096
    // total 25,572,480 B

    hipMemsetAsync(cnt, 0, NT * sizeof(int), stream);
    k_edges<<<(NE + 255) / 256, 256, 0, stream>>>(esrc, edst, cnt, csr);
    k_conv<<<CVB + GNB + PKB, 256, 0, stream>>>(
        train, gene, AF, (u32*)GH,
        (const float*)d_in[4], (const float*)d_in[5], (const float*)d_in[7],
        (const float*)d_in[8], (const float*)d_in[10], (const float*)d_in[12],
        B1h, B1l, B2h, B2l, B3h, B3l, B4h, B4l);
    k_mega<<<NT / 32, 512, 0, stream>>>(
        cnt, csr, GH, AF, B1h, B1l, B2h, B2l, B3h, B3l, B4h, B4l,
        (const float*)d_in[6], (const float*)d_in[9], (const float*)d_in[11],
        (const float*)d_in[13], (float*)d_out);
}

// Round 10
// 179.113 us; speedup vs baseline: 1.2417x; 1.0396x over previous
//
#include <hip/hip_runtime.h>

// WordSAGE on MI355X — fp32 in/out. Round-10 structure (2 kernels + memset):
//   k_prep : ONE kernel, block-ranges = [edges fillpad | train->AF tiles |
//            gene->GH | weight pack]. Edge blocks first so the latency-bound
//            scatter overlaps the streaming converts (same-stream kernels
//            serialize; fusion is the only overlap available).
//   k_mega : phase0 gather-mean from GH into LDS, then fused 4-layer
//            split-bf16 MFMA. Wave = col-group (8 groups); each wave covers
//            BOTH 16-row tiles -> every B byte read once per block
//            (halves L2 B-traffic vs round 9) and 2 indep acc chains.
// Precision: weights/agg/h split hi+lo bf16; train & gene hi-only.

#define NG 2500
#define NT 20000
#define NE 640000
#define NCLS 16
#define CAP 96
#define NTILE 1250   // NT/16

typedef unsigned short u16;
typedef unsigned int u32;

typedef float f32x4 __attribute__((ext_vector_type(4)));
typedef __bf16 bf16x8 __attribute__((ext_vector_type(8)));

__device__ __forceinline__ float b2f(u16 u) { return __uint_as_float(((u32)u) << 16); }
__device__ __forceinline__ float blo(u32 p) { return __uint_as_float(p << 16); }
__device__ __forceinline__ float bhi(u32 p) { return __uint_as_float(p & 0xffff0000u); }
__device__ __forceinline__ u16 f2b(float f) {  // RNE fp32->bf16
    u32 u = __float_as_uint(f);
    return (u16)((u + 0x7fffu + ((u >> 16) & 1u)) >> 16);
}

// ---- sizes ---------------------------------------------------------------
#define B1N 81920   // K=640: train k 0..499, zero 500..511, agg 512..639; N=128
#define B2N 32768   // K=256: h1 (W2s) 0..127, agg (W2n) 128..255; N=128
#define B3N 16384   // K=128 Wc1, N=128
#define B4N 2048    // K=128 Wc2, N=16
#define NEB 2500    // edge blocks
#define CVB NTILE   // 1250 tile-convert blocks
#define GNB 625     // gene-convert blocks
#define PKB 520     // pack blocks

// ---- fused prep -----------------------------------------------------------
__global__ __launch_bounds__(256) void k_prep(
    const int* __restrict__ esrc, const int* __restrict__ edst,
    int* __restrict__ cnt, u16* __restrict__ csr,
    const float* __restrict__ train, const float* __restrict__ gene,
    u16* __restrict__ AF, u32* __restrict__ GH32,
    const float* __restrict__ W1n, const float* __restrict__ W1s,
    const float* __restrict__ W2n, const float* __restrict__ W2s,
    const float* __restrict__ Wc1, const float* __restrict__ Wc2,
    u16* __restrict__ B1h, u16* __restrict__ B1l,
    u16* __restrict__ B2h, u16* __restrict__ B2l,
    u16* __restrict__ B3h, u16* __restrict__ B3l,
    u16* __restrict__ B4h, u16* __restrict__ B4l) {
    int blk = blockIdx.x, t = threadIdx.x;
    if (blk < NEB) {
        int e = blk * 256 + t;
        if (e < NE) {
            unsigned d = (unsigned)edst[e];
            if (d < NT) {
                int slot = atomicAdd(&cnt[d], 1);
                if (slot < CAP) csr[(size_t)d * CAP + slot] = (u16)esrc[e];
            }
        }
        return;
    }
    if (blk < NEB + CVB) {
        // one tile = 16 train rows -> AF fragment order (LDS-staged, coalesced)
        __shared__ __align__(16) u16 L[16 * 520];
        u32* L32 = (u32*)L;
        int tile = blk - NEB;
        for (int i = t; i < 160; i += 256) {  // zero cols 500..519
            int r = i / 10, c = i - r * 10;
            L32[r * 260 + 250 + c] = 0;
        }
        for (int i = t; i < 2000; i += 256) { // 16 rows x 125 float4
            int r = i / 125, c4 = i - r * 125;
            float4 v = *(const float4*)(train + (size_t)(tile * 16 + r) * 500 + c4 * 4);
            int base = r * 260 + c4 * 2;
            L32[base] = (u32)f2b(v.x) | ((u32)f2b(v.y) << 16);
            L32[base + 1] = (u32)f2b(v.z) | ((u32)f2b(v.w) << 16);
        }
        __syncthreads();
#pragma unroll
        for (int it = 0; it < 4; ++it) {      // 16 kk x 64 lanes, coalesced out
            int slot = t + it * 256;
            int kk = slot >> 6, lane = slot & 63;
            int m = lane & 15, q = lane >> 4;
            uint4 v = *(const uint4*)(L + m * 520 + kk * 32 + q * 8);
            *(uint4*)(AF + (((size_t)tile * 16 + kk) * 64 + lane) * 8) = v;
        }
        return;
    }
    if (blk < NEB + CVB + GNB) {
        int idx = (blk - NEB - CVB) * 256 + t;  // < 160000
        float2 v = ((const float2*)gene)[idx];
        GH32[idx] = (u32)f2b(v.x) | ((u32)f2b(v.y) << 16);
        return;
    }
    // ---- weight pack (split hi/lo, B-fragment order) ----
    int idx = (blk - NEB - CVB - GNB) * 256 + t;
    float v = 0.f;
    u16 *ph = 0, *pl = 0;
    int off = 0;
    if (idx < B1N) {
        int j = idx & 7, l = (idx >> 3) & 63, rest = idx >> 9;
        int g = rest & 7, kk = rest >> 3;
        int k = kk * 32 + ((l >> 4) << 3) + j, n = (g << 4) + (l & 15);
        if (k < 500) v = W1s[k * 128 + n];
        else if (k >= 512) v = W1n[(k - 512) * 128 + n];
        ph = B1h; pl = B1l; off = idx;
    } else if (idx < B1N + B2N) {
        int e = idx - B1N;
        int j = e & 7, l = (e >> 3) & 63, rest = e >> 9;
        int g = rest & 7, kk = rest >> 3;
        int k = kk * 32 + ((l >> 4) << 3) + j, n = (g << 4) + (l & 15);
        v = (k < 128) ? W2s[k * 128 + n] : W2n[(k - 128) * 128 + n];
        ph = B2h; pl = B2l; off = e;
    } else if (idx < B1N + B2N + B3N) {
        int e = idx - (B1N + B2N);
        int j = e & 7, l = (e >> 3) & 63, rest = e >> 9;
        int g = rest & 7, kk = rest >> 3;
        int k = kk * 32 + ((l >> 4) << 3) + j, n = (g << 4) + (l & 15);
        v = Wc1[k * 128 + n];
        ph = B3h; pl = B3l; off = e;
    } else if (idx < B1N + B2N + B3N + B4N) {
        int e = idx - (B1N + B2N + B3N);
        int j = e & 7, l = (e >> 3) & 63, kk = e >> 9;
        int k = kk * 32 + ((l >> 4) << 3) + j, n = l & 15;
        v = Wc2[k * 16 + n];
        ph = B4h; pl = B4l; off = e;
    }
    if (ph) {
        u16 hi = f2b(v);
        u16 lo = f2b(v - b2f(hi));
        ph[off] = hi;
        pl[off] = lo;
    }
}

// ---- fused gather + 4-layer MFMA ------------------------------------------
// Block: 512 thr (8 waves), 32 rows (2 tiles). wave = col-group g (0..7);
// each wave handles BOTH row-tiles (acc0/acc1) -> B bytes read once/block.
__global__ __launch_bounds__(512) void k_mega(
    const int* __restrict__ cnt, const u16* __restrict__ csr,
    const u16* __restrict__ GH, const u16* __restrict__ AF,
    const u16* __restrict__ B1h, const u16* __restrict__ B1l,
    const u16* __restrict__ B2h, const u16* __restrict__ B2l,
    const u16* __restrict__ B3h, const u16* __restrict__ B3l,
    const u16* __restrict__ B4h, const u16* __restrict__ B4l,
    const float* __restrict__ b1, const float* __restrict__ b2,
    const float* __restrict__ bc1, const float* __restrict__ bc2,
    float* __restrict__ out) {
    __shared__ __align__(16) u16 SAGh[32 * 136], SAGl[32 * 136];
    __shared__ __align__(16) u16 S1h[32 * 136], S1l[32 * 136];
    __shared__ __align__(16) u16 S2h[32 * 136], S2l[32 * 136];
    int t = threadIdx.x;
    int row0 = blockIdx.x * 32;

    // ---- phase 0: gather-mean of gene-hi into SAG (agg hi/lo) ----
    {
        int r = t >> 4, cg = t & 15;           // row 0..31, col-group 0..15
        int d = row0 + r;
        int ctrue = cnt[d];
        int c = ctrue > CAP ? CAP : ctrue;
        const u16* crow = csr + (size_t)d * CAP;
        float a[8];
#pragma unroll
        for (int p = 0; p < 8; ++p) a[p] = 0.f;
        int j = 0;
        for (; j + 1 < c; j += 2) {
            int s0 = crow[j], s1 = crow[j + 1];
            uint4 p0 = *(const uint4*)(GH + (size_t)s0 * 128 + cg * 8);
            uint4 p1 = *(const uint4*)(GH + (size_t)s1 * 128 + cg * 8);
            a[0] += blo(p0.x); a[1] += bhi(p0.x);
            a[2] += blo(p0.y); a[3] += bhi(p0.y);
            a[4] += blo(p0.z); a[5] += bhi(p0.z);
            a[6] += blo(p0.w); a[7] += bhi(p0.w);
            a[0] += blo(p1.x); a[1] += bhi(p1.x);
            a[2] += blo(p1.y); a[3] += bhi(p1.y);
            a[4] += blo(p1.z); a[5] += bhi(p1.z);
            a[6] += blo(p1.w); a[7] += bhi(p1.w);
        }
        if (j < c) {
            int s = crow[j];
            uint4 p0 = *(const uint4*)(GH + (size_t)s * 128 + cg * 8);
            a[0] += blo(p0.x); a[1] += bhi(p0.x);
            a[2] += blo(p0.y); a[3] += bhi(p0.y);
            a[4] += blo(p0.z); a[5] += bhi(p0.z);
            a[6] += blo(p0.w); a[7] += bhi(p0.w);
        }
        float inv = (ctrue > 0) ? 1.f / (float)ctrue : 0.f;
        int base = (r * 136 + cg * 8) >> 1;    // u32 index (even)
        u32* SH = (u32*)SAGh;
        u32* SL = (u32*)SAGl;
#pragma unroll
        for (int p = 0; p < 4; ++p) {
            float x = a[2 * p] * inv, y = a[2 * p + 1] * inv;
            u16 hx = f2b(x), hy = f2b(y);
            SH[base + p] = (u32)hx | ((u32)hy << 16);
            SL[base + p] = (u32)f2b(x - b2f(hx)) | ((u32)f2b(y - b2f(hy)) << 16);
        }
    }
    __syncthreads();

    int lane = t & 63, g = t >> 6;  // wave index = col-group 0..7
    int m = lane & 15, q = lane >> 4, n16 = lane & 15;
    size_t tile0 = (size_t)blockIdx.x * 2;

    const u16* aB0 = AF + ((tile0 * 16) * 64 + lane) * 8;        // +512/kk
    const u16* aB1 = AF + (((tile0 + 1) * 16) * 64 + lane) * 8;  // +512/kk
    int hr0 = m * 136 + q * 8;
    int hr1 = (16 + m) * 136 + q * 8;
    int cr0 = q * 4, cr1 = 16 + q * 4;
    const f32x4 z4 = {0.f, 0.f, 0.f, 0.f};
    f32x4 acc0 = z4, acc1 = z4;

    // ---- layer1: K=640 (train hi kk0..15 global; agg hi+lo kk16..19 LDS) ----
#pragma unroll 4
    for (int kk = 0; kk < 16; ++kk) {
        bf16x8 a0 = *(const bf16x8*)(aB0 + kk * 512);
        bf16x8 a1 = *(const bf16x8*)(aB1 + kk * 512);
        size_t bo = ((size_t)(kk * 8 + g) * 64 + lane) * 8;
        bf16x8 bh = *(const bf16x8*)(B1h + bo);
        bf16x8 bl = *(const bf16x8*)(B1l + bo);
        acc0 = __builtin_amdgcn_mfma_f32_16x16x32_bf16(a0, bh, acc0, 0, 0, 0);
        acc0 = __builtin_amdgcn_mfma_f32_16x16x32_bf16(a0, bl, acc0, 0, 0, 0);
        acc1 = __builtin_amdgcn_mfma_f32_16x16x32_bf16(a1, bh, acc1, 0, 0, 0);
        acc1 = __builtin_amdgcn_mfma_f32_16x16x32_bf16(a1, bl, acc1, 0, 0, 0);
    }
#pragma unroll
    for (int kk = 16; kk < 20; ++kk) {
        int o = (kk - 16) * 32;
        bf16x8 ah0 = *(const bf16x8*)(SAGh + hr0 + o);
        bf16x8 al0 = *(const bf16x8*)(SAGl + hr0 + o);
        bf16x8 ah1 = *(const bf16x8*)(SAGh + hr1 + o);
        bf16x8 al1 = *(const bf16x8*)(SAGl + hr1 + o);
        size_t bo = ((size_t)(kk * 8 + g) * 64 + lane) * 8;
        bf16x8 bh = *(const bf16x8*)(B1h + bo);
        bf16x8 bl = *(const bf16x8*)(B1l + bo);
        acc0 = __builtin_amdgcn_mfma_f32_16x16x32_bf16(ah0, bh, acc0, 0, 0, 0);
        acc0 = __builtin_amdgcn_mfma_f32_16x16x32_bf16(ah0, bl, acc0, 0, 0, 0);
        acc0 = __builtin_amdgcn_mfma_f32_16x16x32_bf16(al0, bh, acc0, 0, 0, 0);
        acc1 = __builtin_amdgcn_mfma_f32_16x16x32_bf16(ah1, bh, acc1, 0, 0, 0);
        acc1 = __builtin_amdgcn_mfma_f32_16x16x32_bf16(ah1, bl, acc1, 0, 0, 0);
        acc1 = __builtin_amdgcn_mfma_f32_16x16x32_bf16(al1, bh, acc1, 0, 0, 0);
    }
    {
        int n = g * 16 + n16;
        float bias = b1[n];
#pragma unroll
        for (int rg = 0; rg < 4; ++rg) {
            float v0 = acc0[rg] + bias; v0 = v0 > 0.f ? v0 : 0.f;
            float v1 = acc1[rg] + bias; v1 = v1 > 0.f ? v1 : 0.f;
            u16 h0 = f2b(v0), h1v = f2b(v1);
            S1h[(cr0 + rg) * 136 + n] = h0; S1l[(cr0 + rg) * 136 + n] = f2b(v0 - b2f(h0));
            S1h[(cr1 + rg) * 136 + n] = h1v; S1l[(cr1 + rg) * 136 + n] = f2b(v1 - b2f(h1v));
        }
    }
    __syncthreads();

    // ---- layer2: K=256 (h1 kk0..3 S1; agg kk4..7 SAG) ----
    acc0 = z4; acc1 = z4;
#pragma unroll
    for (int kk = 0; kk < 8; ++kk) {
        const u16* Ph = (kk < 4) ? S1h : SAGh;
        const u16* Pl = (kk < 4) ? S1l : SAGl;
        int o = (kk & 3) * 32;
        bf16x8 ah0 = *(const bf16x8*)(Ph + hr0 + o);
        bf16x8 al0 = *(const bf16x8*)(Pl + hr0 + o);
        bf16x8 ah1 = *(const bf16x8*)(Ph + hr1 + o);
        bf16x8 al1 = *(const bf16x8*)(Pl + hr1 + o);
        size_t bo = ((size_t)(kk * 8 + g) * 64 + lane) * 8;
        bf16x8 bh = *(const bf16x8*)(B2h + bo);
        bf16x8 bl = *(const bf16x8*)(B2l + bo);
        acc0 = __builtin_amdgcn_mfma_f32_16x16x32_bf16(ah0, bh, acc0, 0, 0, 0);
        acc0 = __builtin_amdgcn_mfma_f32_16x16x32_bf16(ah0, bl, acc0, 0, 0, 0);
        acc0 = __builtin_amdgcn_mfma_f32_16x16x32_bf16(al0, bh, acc0, 0, 0, 0);
        acc1 = __builtin_amdgcn_mfma_f32_16x16x32_bf16(ah1, bh, acc1, 0, 0, 0);
        acc1 = __builtin_amdgcn_mfma_f32_16x16x32_bf16(ah1, bl, acc1, 0, 0, 0);
        acc1 = __builtin_amdgcn_mfma_f32_16x16x32_bf16(al1, bh, acc1, 0, 0, 0);
    }
    {
        int n = g * 16 + n16;
        float bias = b2[n];
#pragma unroll
        for (int rg = 0; rg < 4; ++rg) {
            float v0 = acc0[rg] + bias; v0 = v0 > 0.f ? v0 : 0.f;
            float v1 = acc1[rg] + bias; v1 = v1 > 0.f ? v1 : 0.f;
            u16 h0 = f2b(v0), h1v = f2b(v1);
            S2h[(cr0 + rg) * 136 + n] = h0; S2l[(cr0 + rg) * 136 + n] = f2b(v0 - b2f(h0));
            S2h[(cr1 + rg) * 136 + n] = h1v; S2l[(cr1 + rg) * 136 + n] = f2b(v1 - b2f(h1v));
        }
    }
    __syncthreads();

    // ---- layer3: K=128 (h2 S2) -> S1 ----
    acc0 = z4; acc1 = z4;
#pragma unroll
    for (int kk = 0; kk < 4; ++kk) {
        int o = kk * 32;
        bf16x8 ah0 = *(const bf16x8*)(S2h + hr0 + o);
        bf16x8 al0 = *(const bf16x8*)(S2l + hr0 + o);
        bf16x8 ah1 = *(const bf16x8*)(S2h + hr1 + o);
        bf16x8 al1 = *(const bf16x8*)(S2l + hr1 + o);
        size_t bo = ((size_t)(kk * 8 + g) * 64 + lane) * 8;
        bf16x8 bh = *(const bf16x8*)(B3h + bo);
        bf16x8 bl = *(const bf16x8*)(B3l + bo);
        acc0 = __builtin_amdgcn_mfma_f32_16x16x32_bf16(ah0, bh, acc0, 0, 0, 0);
        acc0 = __builtin_amdgcn_mfma_f32_16x16x32_bf16(ah0, bl, acc0, 0, 0, 0);
        acc0 = __builtin_amdgcn_mfma_f32_16x16x32_bf16(al0, bh, acc0, 0, 0, 0);
        acc1 = __builtin_amdgcn_mfma_f32_16x16x32_bf16(ah1, bh, acc1, 0, 0, 0);
        acc1 = __builtin_amdgcn_mfma_f32_16x16x32_bf16(ah1, bl, acc1, 0, 0, 0);
        acc1 = __builtin_amdgcn_mfma_f32_16x16x32_bf16(al1, bh, acc1, 0, 0, 0);
    }
    {
        int n = g * 16 + n16;
        float bias = bc1[n];
#pragma unroll
        for (int rg = 0; rg < 4; ++rg) {
            float v0 = acc0[rg] + bias; v0 = v0 > 0.f ? v0 : 0.f;
            float v1 = acc1[rg] + bias; v1 = v1 > 0.f ? v1 : 0.f;
            u16 h0 = f2b(v0), h1v = f2b(v1);
            S1h[(cr0 + rg) * 136 + n] = h0; S1l[(cr0 + rg) * 136 + n] = f2b(v0 - b2f(h0));
            S1h[(cr1 + rg) * 136 + n] = h1v; S1l[(cr1 + rg) * 136 + n] = f2b(v1 - b2f(h1v));
        }
    }
    __syncthreads();

    // ---- layer4: K=128, N=16 (waves 0,1 = tiles 0,1) ----
    if (g < 2) {
        int hr = (g == 0) ? hr0 : hr1;
        int cr = (g == 0) ? cr0 : cr1;
        f32x4 a4 = z4;
#pragma unroll
        for (int kk = 0; kk < 4; ++kk) {
            bf16x8 ah = *(const bf16x8*)(S1h + hr + kk * 32);
            bf16x8 al = *(const bf16x8*)(S1l + hr + kk * 32);
            size_t bo = ((size_t)kk * 64 + lane) * 8;
            bf16x8 bh = *(const bf16x8*)(B4h + bo);
            bf16x8 bl = *(const bf16x8*)(B4l + bo);
            a4 = __builtin_amdgcn_mfma_f32_16x16x32_bf16(ah, bh, a4, 0, 0, 0);
            a4 = __builtin_amdgcn_mfma_f32_16x16x32_bf16(ah, bl, a4, 0, 0, 0);
            a4 = __builtin_amdgcn_mfma_f32_16x16x32_bf16(al, bh, a4, 0, 0, 0);
        }
        float bias = bc2[n16];
#pragma unroll
        for (int rg = 0; rg < 4; ++rg)
            out[(size_t)(row0 + cr + rg) * NCLS + n16] = a4[rg] + bias;
    }
}

extern "C" void kernel_launch(void* const* d_in, const int* in_sizes, int n_in,
                              void* d_out, int out_size, void* d_ws, size_t ws_size,
                              hipStream_t stream) {
    const float* gene = (const float*)d_in[0];
    const float* train = (const float*)d_in[1];
    const int* esrc = (const int*)d_in[2];
    const int* edst = (const int*)d_in[3];

    char* ws = (char*)d_ws;
    int* cnt = (int*)(ws + 0);              //    80000
    u16* csr = (u16*)(ws + 80000);          //  3840000
    u16* AF = (u16*)(ws + 3920000);         // 20480000 (1250*16*64*8 u16)
    u16* GH = (u16*)(ws + 24400000);        //   640000 (2500*128 u16)
    u16* B1h = (u16*)(ws + 25040000);       //   163840
    u16* B1l = (u16*)(ws + 25203840);       //   163840
    u16* B2h = (u16*)(ws + 25367680);       //    65536
    u16* B2l = (u16*)(ws + 25433216);       //    65536
    u16* B3h = (u16*)(ws + 25498752);       //    32768
    u16* B3l = (u16*)(ws + 25531520);       //    32768
    u16* B4h = (u16*)(ws + 25564288);       //     4096
    u16* B4l = (u16*)(ws + 25568384);       //     4096
    // total 25,572,480 B

    hipMemsetAsync(cnt, 0, NT * sizeof(int), stream);
    k_prep<<<NEB + CVB + GNB + PKB, 256, 0, stream>>>(
        esrc, edst, cnt, csr, train, gene, AF, (u32*)GH,
        (const float*)d_in[4], (const float*)d_in[5], (const float*)d_in[7],
        (const float*)d_in[8], (const float*)d_in[10], (const float*)d_in[12],
        B1h, B1l, B2h, B2l, B3h, B3l, B4h, B4l);
    k_mega<<<NT / 32, 512, 0, stream>>>(
        cnt, csr, GH, AF, B1h, B1l, B2h, B2l, B3h, B3l, B4h, B4l,
        (const float*)d_in[6], (const float*)d_in[9], (const float*)d_in[11],
        (const float*)d_in[13], (float*)d_out);
}